// Round 8
// baseline (47.986 us; speedup 1.0000x reference)
//
#include <hip/hip_runtime.h>

// Problem constants (match reference setup_inputs)
#define MAX_REQS   8192
#define MAX_BLOCKS 4096
#define NBT        (MAX_REQS * MAX_BLOCKS)   // 33554432 table entries

typedef int int4v __attribute__((ext_vector_type(4)));

// Kernel 1: copy the full block table, 16B vector grid-stride.
// R7 (nt-store, plain load) = 41.7 us. This round flips polarity:
// Loads NON-TEMPORAL (stream input from HBM, don't allocate in the
// memory-side Infinity Cache). Stores PLAIN (allocate -> the 134 MB output
// working set stays dirty-resident in the 256 MB L3 across graph replays,
// rewritten in place each replay with no HBM writeback while resident).
// Steady-state HBM traffic should drop to ~134 MB read-only per replay.
__global__ void bt_copy_kernel(const int* __restrict__ bt_in,
                               const int* __restrict__ nb_in,
                               int* __restrict__ out) {
    const int4v* __restrict__ src = reinterpret_cast<const int4v*>(bt_in);
    int4v* __restrict__ dst = reinterpret_cast<int4v*>(out);
    const int n4 = NBT / 4;                          // 8388608
    const int stride = gridDim.x * blockDim.x;
    int gid = blockIdx.x * blockDim.x + threadIdx.x;
    for (int i = gid; i < n4; i += stride) {
        int4v v = __builtin_nontemporal_load(&src[i]);  // nt load: no-allocate
        dst[i] = v;                                     // plain store: L3-resident
    }
    // num_blocks pass-through (scatter kernel overrides touched rows later)
    if (gid < MAX_REQS) {
        out[NBT + gid] = nb_in[gid];
    }
}

// Kernel 2 (unchanged from R4): one WAVE (64 lanes) per request.
__global__ void __launch_bounds__(1024)
bt_scatter_wave_kernel(const int* __restrict__ req_indices,
                       const int* __restrict__ cu,          // [num_reqs+1]
                       const int* __restrict__ new_ids,     // [total]
                       const int* __restrict__ overwrite,   // int32 (verified R1)
                       const int* __restrict__ nb_in,       // [MAX_REQS]
                       int* __restrict__ out,
                       int num_reqs) {
    const int flat = blockIdx.x * 1024 + threadIdx.x;
    const int r    = flat >> 6;          // wave-uniform request index
    const int lane = flat & 63;
    if (r >= num_reqs) return;
    const int start = cu[r];
    const int count = cu[r + 1] - start;
    const int row   = req_indices[r];
    const int dst0  = overwrite[r] ? 0 : nb_in[row];
    const long long base = (long long)row * MAX_BLOCKS;
    for (int j = lane; j < count; j += 64) {
        out[base + dst0 + j] = new_ids[start + j];
    }
    if (lane == 0) {
        out[NBT + row] = dst0 + count;
    }
}

extern "C" void kernel_launch(void* const* d_in, const int* in_sizes, int n_in,
                              void* d_out, int out_size, void* d_ws, size_t ws_size,
                              hipStream_t stream) {
    // setup_inputs order:
    // 0 req_indices        int32 [num_reqs]
    // 1 cu_num_new_blocks  int32 [G=1, num_reqs+1]
    // 2 new_block_ids      int32 [G, total]
    // 3 overwrite          int32 [num_reqs]   (nonzero = true; verified R1)
    // 4 block_table_strides int32 [G] (== MAX_BLOCKS, hard-coded)
    // 5 block_table_ptrs   int32 [G]  (unused)
    // 6 num_blocks         int32 [G, MAX_REQS]
    // 7 block_tables       int32 [MAX_REQS, MAX_BLOCKS]
    const int* req_indices = (const int*)d_in[0];
    const int* cu          = (const int*)d_in[1];
    const int* new_ids     = (const int*)d_in[2];
    const int* overwrite   = (const int*)d_in[3];
    const int* nb_in       = (const int*)d_in[6];
    const int* bt_in       = (const int*)d_in[7];
    int* out = (int*)d_out;

    const int num_reqs = in_sizes[0];

    // Copy: 2048 blocks x 256 threads, 16B vector grid-stride over 128 MB.
    bt_copy_kernel<<<2048, 256, 0, stream>>>(bt_in, nb_in, out);

    // Scatter: one wave per request; 16 waves per 1024-thread block.
    const int total_threads = num_reqs * 64;
    const int nblocks = (total_threads + 1023) / 1024;
    bt_scatter_wave_kernel<<<nblocks, 1024, 0, stream>>>(req_indices, cu, new_ids,
                                                         overwrite, nb_in, out, num_reqs);
}

// Round 9
// 41.629 us; speedup vs baseline: 1.1527x; 1.1527x over previous
//
#include <hip/hip_runtime.h>

// Problem constants (match reference setup_inputs)
#define MAX_REQS   8192
#define MAX_BLOCKS 4096
#define NBT        (MAX_REQS * MAX_BLOCKS)   // 33554432 table entries

typedef int int4v __attribute__((ext_vector_type(4)));

// Kernel 1: copy the full block table, 16B vector grid-stride.
// Best measured polarity (R7 = 41.7 us): loads PLAIN (input allocates in the
// 256 MB Infinity Cache and is substantially served from it across replays),
// stores NON-TEMPORAL (output stream doesn't churn the cache; R8 showed the
// mirror config costs +6 us, R1/R4 plain/plain costs +5 us).
__global__ void bt_copy_kernel(const int* __restrict__ bt_in,
                               const int* __restrict__ nb_in,
                               int* __restrict__ out) {
    const int4v* __restrict__ src = reinterpret_cast<const int4v*>(bt_in);
    int4v* __restrict__ dst = reinterpret_cast<int4v*>(out);
    const int n4 = NBT / 4;                          // 8388608
    const int stride = gridDim.x * blockDim.x;
    int gid = blockIdx.x * blockDim.x + threadIdx.x;
    for (int i = gid; i < n4; i += stride) {
        int4v v = src[i];                            // plain load: L3-allocate
        __builtin_nontemporal_store(v, &dst[i]);     // nt store: no-allocate
    }
    // num_blocks pass-through (scatter kernel overrides touched rows later)
    if (gid < MAX_REQS) {
        out[NBT + gid] = nb_in[gid];
    }
}

// Kernel 2: one WAVE (64 lanes) per request. Metadata loads are same-address
// within the wave (broadcast); id load and table store are coalesced 256B.
__global__ void __launch_bounds__(1024)
bt_scatter_wave_kernel(const int* __restrict__ req_indices,
                       const int* __restrict__ cu,          // [num_reqs+1]
                       const int* __restrict__ new_ids,     // [total]
                       const int* __restrict__ overwrite,   // int32 (verified R1)
                       const int* __restrict__ nb_in,       // [MAX_REQS]
                       int* __restrict__ out,
                       int num_reqs) {
    const int flat = blockIdx.x * 1024 + threadIdx.x;
    const int r    = flat >> 6;          // wave-uniform request index
    const int lane = flat & 63;
    if (r >= num_reqs) return;
    const int start = cu[r];
    const int count = cu[r + 1] - start;
    const int row   = req_indices[r];
    const int dst0  = overwrite[r] ? 0 : nb_in[row];
    const long long base = (long long)row * MAX_BLOCKS;
    for (int j = lane; j < count; j += 64) {
        out[base + dst0 + j] = new_ids[start + j];
    }
    if (lane == 0) {
        out[NBT + row] = dst0 + count;
    }
}

extern "C" void kernel_launch(void* const* d_in, const int* in_sizes, int n_in,
                              void* d_out, int out_size, void* d_ws, size_t ws_size,
                              hipStream_t stream) {
    // setup_inputs order:
    // 0 req_indices        int32 [num_reqs]
    // 1 cu_num_new_blocks  int32 [G=1, num_reqs+1]
    // 2 new_block_ids      int32 [G, total]
    // 3 overwrite          int32 [num_reqs]   (nonzero = true; verified R1)
    // 4 block_table_strides int32 [G] (== MAX_BLOCKS, hard-coded)
    // 5 block_table_ptrs   int32 [G]  (unused)
    // 6 num_blocks         int32 [G, MAX_REQS]
    // 7 block_tables       int32 [MAX_REQS, MAX_BLOCKS]
    const int* req_indices = (const int*)d_in[0];
    const int* cu          = (const int*)d_in[1];
    const int* new_ids     = (const int*)d_in[2];
    const int* overwrite   = (const int*)d_in[3];
    const int* nb_in       = (const int*)d_in[6];
    const int* bt_in       = (const int*)d_in[7];
    int* out = (int*)d_out;

    const int num_reqs = in_sizes[0];

    // Copy: 2048 blocks x 256 threads, 16B vector grid-stride over 128 MB.
    bt_copy_kernel<<<2048, 256, 0, stream>>>(bt_in, nb_in, out);

    // Scatter: one wave per request; 16 waves per 1024-thread block.
    const int total_threads = num_reqs * 64;
    const int nblocks = (total_threads + 1023) / 1024;
    bt_scatter_wave_kernel<<<nblocks, 1024, 0, stream>>>(req_indices, cu, new_ids,
                                                         overwrite, nb_in, out, num_reqs);
}